// Round 9
// baseline (85.002 us; speedup 1.0000x reference)
//
#include <hip/hip_runtime.h>

// GPDGaussian: per-pixel 629x3 conv -> (m, S=R^T diag(s) R, s)
// WAVE-PRIVATE design (r7) + register-pressure controls (r9):
//   - amdgpu_waves_per_eu(2,4): allocator targets <=4 waves/EU (budget >=128
//     VGPR) instead of spilling to chase 8 waves/EU (r7's failure mode).
//   - sched_barrier(0) at phase boundaries: stops fill->rot hoisting that
//     buffered cs cells in registers.
// Each wave owns one pixel PAIR; all LDS wave-private; ZERO __syncthreads.
// 2048 blocks x 256 thr (4 waves = 4 pairs = 8 px/block).

#define CCH 34
#define ACH 561
#define HWPIX 4096
#define NPIX 16384
#define NTHR 256
#define CH0 281                  // chunk 0: [0,281), chunk 1: [281,561)
#define VROW 36                  // dwords per row-pair (144B, 16B-aligned)
#define VPX (17 * VROW * 4)      // 2448 B per-pixel V region
#define SH_OFF (2 * VPX)         // 4896: sh (s in f16) offset in wave region
#define WREGB 5056               // wave region: max(cs 4496, V 4896) + sh 136, pad
#define OFF_S 557056
#define OFF_s 19496960
#define LOG2E 1.4426950408889634f

typedef float    f32x2 __attribute__((ext_vector_type(2)));
typedef _Float16 h2    __attribute__((ext_vector_type(2)));

struct Pairs {
    short i[ACH]; short j[ACH];
    constexpr Pairs() : i(), j() {
        int p = 0;
        for (int a = 0; a < CCH - 1; ++a)
            for (int b = a + 1; b < CCH; ++b) { i[p] = (short)a; j[p] = (short)b; ++p; }
    }
};
__device__ constexpr Pairs PR{};

__device__ __forceinline__ float dot2h(h2 a, h2 b, float c) {
#if __has_builtin(__builtin_amdgcn_fdot2)
    return __builtin_amdgcn_fdot2(a, b, c, false);
#else
    return fmaf((float)a[0], (float)b[0], fmaf((float)a[1], (float)b[1], c));
#endif
}

__device__ __forceinline__ void rot2(f32x2& Ri, f32x2& Rj, f32x2 c2, f32x2 s2) {
    f32x2 t1, t2;
    asm("v_pk_mul_f32 %0, %1, %2" : "=v"(t1) : "v"(s2), "v"(Rj));
    asm("v_pk_mul_f32 %0, %1, %2" : "=v"(t2) : "v"(s2), "v"(Ri));
    asm("v_pk_fma_f32 %0, %1, %2, %3" : "=v"(Ri) : "v"(c2), "v"(Ri), "v"(t1));
    asm("v_pk_fma_f32 %0, %1, %2, %3 neg_lo:[0,0,1] neg_hi:[0,0,1]"
        : "=v"(Rj) : "v"(c2), "v"(Rj), "v"(t2));
}

template <int P0, int P1>
__device__ __forceinline__ void apply_rots(f32x2* R2, const float4* cs) {
    #pragma unroll
    for (int k = P0; k < P1; ++k) {
        float4 cc = cs[k - P0];                 // broadcast b128 (1 addr/wave)
        f32x2 c2; c2[0] = cc.x; c2[1] = cc.y;
        f32x2 s2; s2[0] = cc.z; s2[1] = cc.w;
        rot2(R2[PR.i[k]], R2[PR.j[k]], c2, s2);
    }
}

__device__ __forceinline__ float2 cs_of(float wv) {
    // angle = pi*tanh(wv); HW cos/sin take revolutions: tanh(wv)/2
    float e  = __builtin_amdgcn_exp2f((2.0f * LOG2E) * wv);
    float tt = 1.0f - 2.0f * __builtin_amdgcn_rcpf(e + 1.0f);
    float rv = 0.5f * tt;
    return make_float2(__builtin_amdgcn_cosf(rv), __builtin_amdgcn_sinf(rv));
}

// wave-private fill: lane handles angles {lane, lane+64, ...} of [G0,G0+LEN)
template <int G0, int LEN>
__device__ __forceinline__ void fill_cs(const float* __restrict__ Wm,
                                        const float* __restrict__ bvec,
                                        char* wreg, int lane,
                                        float xA0, float xA1, float xA2,
                                        float xB0, float xB1, float xB2) {
    for (int l = lane; l < LEN; l += 64) {
        int ch = 2 * CCH + G0 + l;
        float w0 = Wm[ch * 3 + 0], w1 = Wm[ch * 3 + 1], w2 = Wm[ch * 3 + 2];
        float bb = bvec[ch];
        float2 A = cs_of(fmaf(w0, xA0, fmaf(w1, xA1, w2 * xA2)) + bb);
        float2 B = cs_of(fmaf(w0, xB0, fmaf(w1, xB1, w2 * xB2)) + bb);
        float4 cell; cell.x = A.x; cell.y = B.x; cell.z = A.y; cell.w = B.y;
        *(float4*)(wreg + l * 16) = cell;       // dense b128, conflict-free
    }
}

__global__ __launch_bounds__(NTHR)
__attribute__((amdgpu_waves_per_eu(2, 4)))
void gpd_kernel(
    const float* __restrict__ x,     // (4,3,64,64)
    const float* __restrict__ Wm,    // (629,3)
    const float* __restrict__ bvec,  // (629,)
    float* __restrict__ out)
{
    __shared__ alignas(16) char lds[4 * WREGB];    // 20224 B

    const int t    = threadIdx.x;
    const int lane = t & 63;
    const int wvid = t >> 6;
    char* wreg = lds + wvid * WREGB;

    const int pairp = blockIdx.x * 4 + wvid;       // 0..8191, exact
    const int pxA = 2 * pairp, pxB = pxA + 1;
    const int bA = pxA >> 12, hwA = pxA & 4095;
    const int bB = pxB >> 12, hwB = pxB & 4095;

    const float xA0 = x[(bA*3+0)*HWPIX + hwA];
    const float xA1 = x[(bA*3+1)*HWPIX + hwA];
    const float xA2 = x[(bA*3+2)*HWPIX + hwA];
    const float xB0 = x[(bB*3+0)*HWPIX + hwB];
    const float xB1 = x[(bB*3+1)*HWPIX + hwB];
    const float xB2 = x[(bB*3+2)*HWPIX + hwB];

    _Float16* sh = (_Float16*)(wreg + SH_OFF);     // [2][34] s in f16

    // ---- Phase A: mean + s, 136 tasks over 64 lanes ----
    for (int o = lane; o < 2 * 68; o += 64) {
        int half = o >= 68;
        int ch   = o - 68 * half;
        float x0 = half ? xB0 : xA0;
        float x1 = half ? xB1 : xA1;
        float x2 = half ? xB2 : xA2;
        int px = pxA + half;
        int b = px >> 12, hw = px & 4095;
        float wvv = fmaf(Wm[ch*3+0], x0,
                    fmaf(Wm[ch*3+1], x1, Wm[ch*3+2] * x2)) + bvec[ch];
        if (ch < CCH) {
            out[(size_t)px * CCH + ch] = wvv;                     // mean
        } else {
            float e  = __builtin_amdgcn_exp2f(-wvv * LOG2E);
            float sg = __builtin_amdgcn_rcpf(1.0f + e);
            float sv = fmaf(999.999f, sg, 0.001f);                // s
            int c = ch - CCH;
            out[OFF_s + (size_t)(b * CCH + c) * HWPIX + hw] = sv;
            sh[half * CCH + c] = (_Float16)sv;
        }
    }

    const int m = lane;                            // R row (lanes 0..33)
    const bool act = (lane < CCH);

    f32x2 R2[CCH];
    #pragma unroll
    for (int k = 0; k < CCH; ++k) { R2[k][0] = (k == m) ? 1.0f : 0.0f; R2[k][1] = R2[k][0]; }

    // ---- chunk 0: fill cs then rotate (wave-private; fences stop hoisting) ----
    __builtin_amdgcn_sched_barrier(0);
    fill_cs<0, CH0>(Wm, bvec, wreg, lane, xA0, xA1, xA2, xB0, xB1, xB2);
    __builtin_amdgcn_sched_barrier(0);
    if (act) apply_rots<0, CH0>(R2, (const float4*)wreg);
    __builtin_amdgcn_sched_barrier(0);
    // ---- chunk 1 ----
    fill_cs<CH0, ACH - CH0>(Wm, bvec, wreg, lane, xA0, xA1, xA2, xB0, xB1, xB2);
    __builtin_amdgcn_sched_barrier(0);
    if (act) apply_rots<CH0, ACH>(R2, (const float4*)wreg);
    __builtin_amdgcn_sched_barrier(0);

    // ---- pack R to f16 pairs; R2 dies ----
    h2 Rh[CCH];
    #pragma unroll
    for (int n = 0; n < CCH; ++n) {
#if __has_builtin(__builtin_amdgcn_cvt_pkrtz)
        Rh[n] = __builtin_bit_cast(h2, __builtin_amdgcn_cvt_pkrtz(R2[n][0], R2[n][1]));
#else
        h2 hv; hv[0] = (_Float16)R2[n][0]; hv[1] = (_Float16)R2[n][1]; Rh[n] = hv;
#endif
    }

    // ---- stage V for both pixels (pairs of rows 2q,2q+1 packed per dword) ----
    if (act) {
        char* baseA = wreg + (m >> 1) * (VROW * 4) + (m & 1) * 2;
        #pragma unroll
        for (int n = 0; n < CCH; ++n) {
            *(_Float16*)(baseA + n * 4)       = Rh[n][0];
            *(_Float16*)(baseA + VPX + n * 4) = Rh[n][1];
        }
    }
    __builtin_amdgcn_sched_barrier(0);

    // ---- phase C: S row m for px A then px B ----
    #pragma unroll
    for (int h = 0; h < 2; ++h) {
        if (act) {
            const unsigned* vb = (const unsigned*)(wreg + h * VPX);
            const _Float16* shp = sh + h * CCH;
            float acc[CCH];
            #pragma unroll
            for (int n = 0; n < CCH; ++n) acc[n] = 0.0f;
            for (int mp = 0; mp < 17; ++mp) {
                const unsigned* row = vb + mp * VROW;
                h2 vk = __builtin_bit_cast(h2, row[m]) * *(const h2*)(shp + 2 * mp);
                #pragma unroll
                for (int g = 0; g < 8; ++g) {
                    uint4 rr = *(const uint4*)(row + 4 * g);
                    acc[4*g+0] = dot2h(vk, __builtin_bit_cast(h2, rr.x), acc[4*g+0]);
                    acc[4*g+1] = dot2h(vk, __builtin_bit_cast(h2, rr.y), acc[4*g+1]);
                    acc[4*g+2] = dot2h(vk, __builtin_bit_cast(h2, rr.z), acc[4*g+2]);
                    acc[4*g+3] = dot2h(vk, __builtin_bit_cast(h2, rr.w), acc[4*g+3]);
                }
                uint2 rr2 = *(const uint2*)(row + 32);
                acc[32] = dot2h(vk, __builtin_bit_cast(h2, rr2.x), acc[32]);
                acc[33] = dot2h(vk, __builtin_bit_cast(h2, rr2.y), acc[33]);
            }
            float* os = out + OFF_S + (size_t)(pxA + h) * (CCH * CCH) + m * CCH;
            #pragma unroll
            for (int n2 = 0; n2 < 17; ++n2) {
                float2 v; v.x = acc[2*n2]; v.y = acc[2*n2+1];
                *(float2*)(os + 2 * n2) = v;
            }
        }
    }
}

extern "C" void kernel_launch(void* const* d_in, const int* in_sizes, int n_in,
                              void* d_out, int out_size, void* d_ws, size_t ws_size,
                              hipStream_t stream) {
    const float* x  = (const float*)d_in[0];
    const float* W  = (const float*)d_in[1];
    const float* bv = (const float*)d_in[2];
    float* out = (float*)d_out;
    hipLaunchKernelGGL(gpd_kernel, dim3(NPIX / 8), dim3(NTHR), 0, stream,
                       x, W, bv, out);   // 2048 blocks, 1 pair per wave
}

// Round 10
// 75.368 us; speedup vs baseline: 1.1278x; 1.1278x over previous
//
#include <hip/hip_runtime.h>

// GPDGaussian: per-pixel 629x3 conv -> (m, S=R^T diag(s) R, s)
// r10 = r8 block-packed structure + grid-supply fix + rot operand fix:
//  - 128-thread blocks, 3 pairs (6 px): 2731 blocks = 10.7 blocks/CU supply
//    (r8's 1171 blocks = 4.6/CU starved occupancy at 28%).
//  - c2/s2 loaded as typed f32x2 from LDS (aligned pairs direct to v_pk asm
//    operands; r5-r9 built them from float4 lanes -> ~4 v_mov per rotation).
//  - 2 cs chunks, ~10 barriers. launch_bounds(128,4): 128-VGPR no-spill budget.

#define CCH 34
#define ACH 561
#define HWPIX 4096
#define NPIX 16384
#define PXB 6                   // pixels per block
#define NPRB 3                  // pairs per block
#define NTHR 128
#define CH0 281                 // chunk 0: [0,281), chunk 1: [281,561)
#define CSPAIR (281 * 16)       // cs bytes per pair per chunk (4496)
#define VROW 36                 // V row-pair stride in dwords (144B)
#define VPX (17 * VROW * 4)     // 2448 B per-pixel V region
#define OFF_S 557056
#define OFF_s 19496960
#define LOG2E 1.4426950408889634f

typedef float    f32x2 __attribute__((ext_vector_type(2)));
typedef _Float16 h2    __attribute__((ext_vector_type(2)));

struct Pairs {
    short i[ACH]; short j[ACH];
    constexpr Pairs() : i(), j() {
        int p = 0;
        for (int a = 0; a < CCH - 1; ++a)
            for (int b = a + 1; b < CCH; ++b) { i[p] = (short)a; j[p] = (short)b; ++p; }
    }
};
__device__ constexpr Pairs PR{};

__device__ __forceinline__ float dot2h(h2 a, h2 b, float c) {
#if __has_builtin(__builtin_amdgcn_fdot2)
    return __builtin_amdgcn_fdot2(a, b, c, false);
#else
    return fmaf((float)a[0], (float)b[0], fmaf((float)a[1], (float)b[1], c));
#endif
}

// Givens rotation on packed rows: Ri' = c*Ri + s*Rj ; Rj' = c*Rj - s*Ri
__device__ __forceinline__ void rot2(f32x2& Ri, f32x2& Rj, f32x2 c2, f32x2 s2) {
    f32x2 t1, t2;
    asm("v_pk_mul_f32 %0, %1, %2" : "=v"(t1) : "v"(s2), "v"(Rj));
    asm("v_pk_mul_f32 %0, %1, %2" : "=v"(t2) : "v"(s2), "v"(Ri));
    asm("v_pk_fma_f32 %0, %1, %2, %3" : "=v"(Ri) : "v"(c2), "v"(Ri), "v"(t1));
    asm("v_pk_fma_f32 %0, %1, %2, %3 neg_lo:[0,0,1] neg_hi:[0,0,1]"
        : "=v"(Rj) : "v"(c2), "v"(Rj), "v"(t2));
}

template <int P0, int P1>
__device__ __forceinline__ void apply_rots(f32x2* R2, const f32x2* cs2) {
    #pragma unroll
    for (int k = P0; k < P1; ++k) {
        f32x2 c2 = cs2[2 * (k - P0)];       // typed b64 loads -> aligned pairs,
        f32x2 s2 = cs2[2 * (k - P0) + 1];   // no marshalling movs into the asm
        rot2(R2[PR.i[k]], R2[PR.j[k]], c2, s2);
    }
}

__device__ __forceinline__ float2 cs_of(float wv) {
    // angle = pi*tanh(wv); HW cos/sin take revolutions: tanh(wv)/2
    float e  = __builtin_amdgcn_exp2f((2.0f * LOG2E) * wv);
    float tt = 1.0f - 2.0f * __builtin_amdgcn_rcpf(e + 1.0f);
    float rv = 0.5f * tt;
    return make_float2(__builtin_amdgcn_cosf(rv), __builtin_amdgcn_sinf(rv));
}

// one thread computes BOTH pixels of its pair for angle l -> one b128 write
template <int G0, int LEN>
__device__ __forceinline__ void fill_cs(const float* __restrict__ Wm,
                                        const float* __restrict__ bvec,
                                        const float* xs, char* ldsbuf,
                                        int npr, int t) {
    for (int o = t; o < npr * LEN; o += NTHR) {
        int pr = (int)((unsigned)o / (unsigned)LEN);
        int l  = o - pr * LEN;
        int ch = 2 * CCH + G0 + l;
        float w0 = Wm[ch * 3 + 0], w1 = Wm[ch * 3 + 1], w2 = Wm[ch * 3 + 2];
        float bb = bvec[ch];
        int pa = 2 * pr, pb = 2 * pr + 1;       // npx always even
        float2 A = cs_of(fmaf(w0, xs[pa*3+0], fmaf(w1, xs[pa*3+1], w2 * xs[pa*3+2])) + bb);
        float2 B = cs_of(fmaf(w0, xs[pb*3+0], fmaf(w1, xs[pb*3+1], w2 * xs[pb*3+2])) + bb);
        float4 cell; cell.x = A.x; cell.y = B.x; cell.z = A.y; cell.w = B.y;
        *(float4*)(ldsbuf + pr * CSPAIR + l * 16) = cell;   // dense b128
    }
}

__global__ __launch_bounds__(NTHR, 4) void gpd_kernel(
    const float* __restrict__ x,     // (4,3,64,64)
    const float* __restrict__ Wm,    // (629,3)
    const float* __restrict__ bvec,  // (629,)
    float* __restrict__ out)
{
    __shared__ alignas(16) char ldsbuf[NPRB * CSPAIR];  // 13488 B (cs | V overlay)
    __shared__ _Float16 lds_sh[PXB * CCH];              // s in f16
    __shared__ float xs[PXB * 3];

    const int t   = threadIdx.x;
    const int p0  = blockIdx.x * PXB;
    const int npx = min(PXB, NPIX - p0);                // always even
    const int npr = npx >> 1;

    // ---- stage x into LDS ----
    for (int i = t; i < npx * 3; i += NTHR) {
        int px = (int)((unsigned)i / 3u); int c = i - px * 3;
        int p = p0 + px; int b = p >> 12; int hw = p & 4095;
        xs[i] = x[(b * 3 + c) * HWPIX + hw];
    }
    __syncthreads();

    // ---- A: mean + s channels ----
    for (int o = t; o < npx * 68; o += NTHR) {
        int q = (int)((unsigned)o / 68u); int ch = o - q * 68;
        int p = p0 + q; int b = p >> 12; int hw = p & 4095;
        float wv = fmaf(Wm[ch*3+0], xs[q*3+0],
                   fmaf(Wm[ch*3+1], xs[q*3+1], Wm[ch*3+2] * xs[q*3+2])) + bvec[ch];
        if (ch < CCH) {
            out[(size_t)p * CCH + ch] = wv;                       // mean
        } else {
            float e  = __builtin_amdgcn_exp2f(-wv * LOG2E);
            float sg = __builtin_amdgcn_rcpf(1.0f + e);
            float sv = fmaf(999.999f, sg, 0.001f);                // s
            int c = ch - CCH;
            out[OFF_s + (size_t)(b * CCH + c) * HWPIX + hw] = sv;
            lds_sh[q * CCH + c] = (_Float16)sv;
        }
    }

    const int pr = t / CCH;                  // pair within block (0..2)
    const int m  = t - pr * CCH;             // R row owned by this thread
    const bool act = (t < npr * CCH);

    f32x2 R2[CCH];
    #pragma unroll
    for (int k = 0; k < CCH; ++k) { R2[k][0] = (k == m) ? 1.0f : 0.0f; R2[k][1] = R2[k][0]; }

    // ---- chunk 0: fill cos/sin -> rotate ----
    fill_cs<0, CH0>(Wm, bvec, xs, ldsbuf, npr, t);
    __syncthreads();
    if (act) apply_rots<0, CH0>(R2, (const f32x2*)(ldsbuf + pr * CSPAIR));
    __syncthreads();
    // ---- chunk 1 ----
    fill_cs<CH0, ACH - CH0>(Wm, bvec, xs, ldsbuf, npr, t);
    __syncthreads();
    if (act) apply_rots<CH0, ACH>(R2, (const f32x2*)(ldsbuf + pr * CSPAIR));
    __syncthreads();

    // ---- pack R to f16 pairs once; R2 dies here ----
    h2 Rh[CCH];
    #pragma unroll
    for (int n = 0; n < CCH; ++n) {
#if __has_builtin(__builtin_amdgcn_cvt_pkrtz)
        Rh[n] = __builtin_bit_cast(h2, __builtin_amdgcn_cvt_pkrtz(R2[n][0], R2[n][1]));
#else
        h2 hv; hv[0] = (_Float16)R2[n][0]; hv[1] = (_Float16)R2[n][1]; Rh[n] = hv;
#endif
    }

    // ---- phase C in 2 rounds: stage V (3 px), compute their S rows ----
    #pragma unroll
    for (int h = 0; h < 2; ++h) {
        if (act) {
            // rows (2mp,2mp+1) packed per dword; thread m writes half (m&1)
            char* base = ldsbuf + pr * VPX + (m >> 1) * (VROW * 4) + (m & 1) * 2;
            #pragma unroll
            for (int n = 0; n < CCH; ++n)
                *(_Float16*)(base + n * 4) = Rh[n][h];
        }
        __syncthreads();

        if (act) {
            const int px = 2 * pr + h;
            const unsigned* vb = (const unsigned*)(ldsbuf + pr * VPX);
            const _Float16* sh = lds_sh + px * CCH;
            float acc[CCH];
            #pragma unroll
            for (int n = 0; n < CCH; ++n) acc[n] = 0.0f;
            for (int mp = 0; mp < 17; ++mp) {
                const unsigned* row = vb + mp * VROW;
                h2 vk = __builtin_bit_cast(h2, row[m]) * *(const h2*)(sh + 2 * mp);
                #pragma unroll
                for (int g = 0; g < 8; ++g) {
                    uint4 rr = *(const uint4*)(row + 4 * g);
                    acc[4*g+0] = dot2h(vk, __builtin_bit_cast(h2, rr.x), acc[4*g+0]);
                    acc[4*g+1] = dot2h(vk, __builtin_bit_cast(h2, rr.y), acc[4*g+1]);
                    acc[4*g+2] = dot2h(vk, __builtin_bit_cast(h2, rr.z), acc[4*g+2]);
                    acc[4*g+3] = dot2h(vk, __builtin_bit_cast(h2, rr.w), acc[4*g+3]);
                }
                uint2 rr2 = *(const uint2*)(row + 32);
                acc[32] = dot2h(vk, __builtin_bit_cast(h2, rr2.x), acc[32]);
                acc[33] = dot2h(vk, __builtin_bit_cast(h2, rr2.y), acc[33]);
            }
            float* os = out + OFF_S + (size_t)(p0 + px) * (CCH * CCH) + m * CCH;
            #pragma unroll
            for (int n2 = 0; n2 < 17; ++n2) {
                float2 v; v.x = acc[2*n2]; v.y = acc[2*n2+1];
                *(float2*)(os + 2 * n2) = v;
            }
        }
        __syncthreads();        // V region reused by round 2
    }
}

extern "C" void kernel_launch(void* const* d_in, const int* in_sizes, int n_in,
                              void* d_out, int out_size, void* d_ws, size_t ws_size,
                              hipStream_t stream) {
    const float* x  = (const float*)d_in[0];
    const float* W  = (const float*)d_in[1];
    const float* bv = (const float*)d_in[2];
    float* out = (float*)d_out;
    const int nblk = (NPIX + PXB - 1) / PXB;   // 2731
    hipLaunchKernelGGL(gpd_kernel, dim3(nblk), dim3(NTHR), 0, stream,
                       x, W, bv, out);
}